// Round 10
// baseline (316.544 us; speedup 1.0000x reference)
//
#include <hip/hip_runtime.h>
#include <hip/hip_bf16.h>
#include <hip/hip_cooperative_groups.h>

namespace cg = cooperative_groups;

// MultiScaleTimeMixer: B=64, T=512, C=512, T2=256
// bf16 MFMA pipeline, intermediates TRANSPOSED ([N x K] for next GEMM).
// R10: single cooperative mega-kernel, 4 phases with grid.sync() between:
//   P0 pre1(stats+xbf+WtT) -> P1 [G3|norm|wprep] -> P2 [G1|G4] -> P3 [G2|G5].
// Work assignment per phase identical to R9 -> bit-identical output.

#define NB 64

typedef __bf16 bf16x8 __attribute__((ext_vector_type(8)));
typedef __bf16 bf16x4 __attribute__((ext_vector_type(4)));
typedef float f32x4 __attribute__((ext_vector_type(4)));

#define AS_GLOBAL __attribute__((address_space(1)))
#define AS_LDS    __attribute__((address_space(3)))

// ---- P0 body: per-batch partial stats + xbf cast (vb 0..255) + WtT prep ----
__device__ __forceinline__ void pre1_body(
    int vb, char* smem,
    const float* __restrict__ x, float* __restrict__ part,
    __bf16* __restrict__ xbf, const float* __restrict__ cw,
    __bf16* __restrict__ WtT) {
  if (vb < 256) {
    int b = vb >> 2, q = vb & 3;
    size_t base = (size_t)b * 262144 + (size_t)q * 65536;
    const float4* xb = (const float4*)(x + base);
    bf16x4* xo = (bf16x4*)(xbf + base);
    float s = 0.f, ss = 0.f;
    for (int it = 0; it < 64; ++it) {
      int idx = threadIdx.x + 256 * it;
      float4 v = xb[idx];
      s += (v.x + v.y) + (v.z + v.w);
      ss += (v.x * v.x + v.y * v.y) + (v.z * v.z + v.w * v.w);
      bf16x4 o;
      o[0] = (__bf16)v.x; o[1] = (__bf16)v.y; o[2] = (__bf16)v.z; o[3] = (__bf16)v.w;
      xo[idx] = o;
    }
    float* ls = (float*)smem;
    float* lss = ls + 256;
    ls[threadIdx.x] = s; lss[threadIdx.x] = ss;
    __syncthreads();
    for (int off = 128; off > 0; off >>= 1) {
      if (threadIdx.x < off) {
        ls[threadIdx.x] += ls[threadIdx.x + off];
        lss[threadIdx.x] += lss[threadIdx.x + off];
      }
      __syncthreads();
    }
    if (threadIdx.x == 0) { part[vb * 2] = ls[0]; part[vb * 2 + 1] = lss[0]; }
    __syncthreads();   // smem reused by next grid-stride iteration
    return;
  }
  // WtT[o][k*512+i] = cw[o][i*2+k]   (B^T layout [512][1024])
  int idx = (vb - 256) * 256 + threadIdx.x;  // 512*1024
  int o = idx >> 10, r = idx & 1023;
  int i = r & 511, k = r >> 9;
  WtT[idx] = (__bf16)cw[(size_t)o * 1024 + i * 2 + k];
}

// ---- weight prep body (P1 tail): tril-mask + bf16 cast for w1..w4 ----
__device__ __forceinline__ void wprep_body(
    int vb, const float* __restrict__ w1, const float* __restrict__ w2,
    const float* __restrict__ w3, const float* __restrict__ w4,
    __bf16* __restrict__ w1b, __bf16* __restrict__ w2b,
    __bf16* __restrict__ w3b, __bf16* __restrict__ w4b) {
  int idx = vb * 256 + threadIdx.x;
  if (idx < 262144) { int i = idx >> 9, j = idx & 511; w1b[idx] = (__bf16)(j <= i ? w1[idx] : 0.f); return; }
  idx -= 262144;
  if (idx < 262144) { int i = idx >> 9, j = idx & 511; w2b[idx] = (__bf16)(j <= i ? w2[idx] : 0.f); return; }
  idx -= 262144;
  if (idx < 65536) { int i = idx >> 8, j = idx & 255; w3b[idx] = (__bf16)(j <= i ? w3[idx] : 0.f); return; }
  idx -= 65536;
  { int i = idx >> 8, j = idx & 255; w4b[idx] = (__bf16)(j <= i ? w4[idx] : 0.f); }
}

// ---------------- GEMM body: A [MxK] rm, Bt [NxK] rm (bf16); D^T store ----------------
// 128x128 tile, 4 waves of 64x64 (4x4 frags). LDS: row r (128B), 16B-chunk s holds
// global chunk s ^ (r&7); gload_lds linear dest, source pre-swizzled (rule #21).
// XCD-chunked swizzle, runtime lgx (nwg%8==0). MASKK: tril A -> Kend = bm+128.
template <bool MASKK, bool HSW, bool ROWB, bool COLB, bool OUTBF>
__device__ __forceinline__ void gemm_body(
    int bid, int lgx, __bf16* As, __bf16* Bs,
    const __bf16* __restrict__ A, long sAb,
    const __bf16* __restrict__ Bt, long sBb,
    void* __restrict__ Cm, long sCb,
    const float* __restrict__ bias,
    int K, int ldc, int c_off) {
  const int tid = threadIdx.x;
  const int lane = tid & 63, wid = tid >> 6;
  const int wm = (wid >> 1) * 64, wn = (wid & 1) * 64;
  const int lr = lane & 15, lg = lane >> 4;

  const int nid = ((bid & 7) << (lgx + 5)) | (bid >> 3);
  const int bm = (nid & ((1 << lgx) - 1)) * 128;
  const int bn = ((nid >> lgx) & 3) * 128;
  const int bz = nid >> (lgx + 2);

  const int srg = lane >> 3;                  // row within 8-row group == (row&7)
  const int ssrc = ((lane & 7) ^ srg) << 3;   // pre-swizzled source chunk (elems)

  const __bf16* gA[4];
  const __bf16* gB[4];
#pragma unroll
  for (int p = 0; p < 4; ++p) {
    int row = p * 32 + wid * 8 + srg;
    gA[p] = A + (size_t)bz * sAb + (size_t)(bm + row) * K + ssrc;
    gB[p] = Bt + (size_t)bz * sBb + (size_t)(bn + row) * K + ssrc;
  }

  f32x4 acc[4][4] = {};

  const int Kend = MASKK ? (bm + 128) : K;   // tril: k >= bm+128 hits zeros in A
  for (int k0 = 0; k0 < Kend; k0 += 64) {
#pragma unroll
    for (int p = 0; p < 4; ++p) {
      __builtin_amdgcn_global_load_lds(
          (const AS_GLOBAL void*)gA[p],
          (AS_LDS void*)&As[(p * 32 + wid * 8) * 64], 16, 0, 0);
      __builtin_amdgcn_global_load_lds(
          (const AS_GLOBAL void*)gB[p],
          (AS_LDS void*)&Bs[(p * 32 + wid * 8) * 64], 16, 0, 0);
      gA[p] += 64;
      gB[p] += 64;
    }
    __syncthreads();
#pragma unroll
    for (int kk = 0; kk < 64; kk += 32) {
      bf16x8 af[4], bfv[4];
#pragma unroll
      for (int f = 0; f < 4; ++f) {
        int ar = wm + f * 16 + lr;
        af[f] = *(const bf16x8*)&As[ar * 64 + ((kk + lg * 8) ^ ((ar & 7) << 3))];
        int br = wn + f * 16 + lr;
        bfv[f] = *(const bf16x8*)&Bs[br * 64 + ((kk + lg * 8) ^ ((br & 7) << 3))];
      }
#pragma unroll
      for (int i = 0; i < 4; ++i)
#pragma unroll
        for (int j = 0; j < 4; ++j)
          acc[i][j] = __builtin_amdgcn_mfma_f32_16x16x32_bf16(af[i], bfv[j], acc[i][j], 0, 0, 0);
    }
    __syncthreads();
  }

  // epilogue: D[row][col]: col = lane&15 (+16j), row = (lane>>4)*4+r (+16i). store D^T.
#pragma unroll
  for (int i = 0; i < 4; ++i) {
    int row0 = bm + wm + i * 16 + lg * 4;
    float rb0 = 0.f, rb1 = 0.f, rb2 = 0.f, rb3 = 0.f;
    if (ROWB) { rb0 = bias[row0]; rb1 = bias[row0 + 1]; rb2 = bias[row0 + 2]; rb3 = bias[row0 + 3]; }
#pragma unroll
    for (int j = 0; j < 4; ++j) {
      int col = bn + wn + j * 16 + lr;
      float cbv = COLB ? bias[col] : 0.f;
      float v[4] = {acc[i][j][0] + rb0 + cbv, acc[i][j][1] + rb1 + cbv,
                    acc[i][j][2] + rb2 + cbv, acc[i][j][3] + rb3 + cbv};
      if (HSW) {
#pragma unroll
        for (int r = 0; r < 4; ++r) {
          float u = fminf(fmaxf(v[r] + 3.f, 0.f), 6.f);
          v[r] = v[r] * u * (1.f / 6.f);
        }
      }
      if (OUTBF) {
        __bf16* C = (__bf16*)Cm + (size_t)bz * sCb;
        bf16x4 o;
        o[0] = (__bf16)v[0]; o[1] = (__bf16)v[1]; o[2] = (__bf16)v[2]; o[3] = (__bf16)v[3];
        *(bf16x4*)&C[(size_t)col * ldc + c_off + row0] = o;
      } else {
        float* C = (float*)Cm + (size_t)bz * sCb;
        *(float4*)&C[(size_t)col * ldc + c_off + row0] =
            make_float4(v[0], v[1], v[2], v[3]);
      }
    }
  }
}

// ---- norm body: XnT[b][c][t] = bf16(((bf16(x)-mean)*istd)*g + be), 64x64 tile ----
__device__ __forceinline__ void norm_body(
    int bid, char* smem,
    const __bf16* __restrict__ xbf, const float* __restrict__ g,
    const float* __restrict__ be, const float* __restrict__ part,
    __bf16* __restrict__ XnT) {
  float (*ls)[65] = (float(*)[65])smem;
  int b = bid >> 6;
  int r = bid & 63;
  int bc = (r & 7) * 64;   // c tile
  int bt = (r >> 3) * 64;  // t tile
  int tid = threadIdx.x;
  float s = 0.f, ss = 0.f;
#pragma unroll
  for (int q = 0; q < 4; ++q) { s += part[(b * 4 + q) * 2]; ss += part[(b * 4 + q) * 2 + 1]; }
  float mean = s * (1.f / 262144.f);
  float istd = rsqrtf(ss * (1.f / 262144.f) - mean * mean + 1e-5f);

  const __bf16* xb = xbf + (size_t)b * 262144;
  int row = tid >> 3;          // 0..31
  int ch = (tid & 7) * 8;      // c chunk
  __syncthreads();             // guard smem reuse across grid-stride iterations
#pragma unroll
  for (int p = 0; p < 2; ++p) {
    int t = p * 32 + row;
    bf16x8 v = *(const bf16x8*)&xb[(size_t)(bt + t) * 512 + bc + ch];
#pragma unroll
    for (int j = 0; j < 8; ++j) ls[t][ch + j] = (float)v[j];
  }
  __syncthreads();
  int cr = tid >> 3;
  int t0 = (tid & 7) * 8;
  __bf16* xnb = XnT + (size_t)b * 262144;
#pragma unroll
  for (int p = 0; p < 2; ++p) {
    int cg = bc + p * 32 + cr;
    int cl = p * 32 + cr;
    float4 g0 = *(const float4*)&g[(size_t)cg * 512 + bt + t0];
    float4 g1 = *(const float4*)&g[(size_t)cg * 512 + bt + t0 + 4];
    float4 e0 = *(const float4*)&be[(size_t)cg * 512 + bt + t0];
    float4 e1 = *(const float4*)&be[(size_t)cg * 512 + bt + t0 + 4];
    float gv[8] = {g0.x, g0.y, g0.z, g0.w, g1.x, g1.y, g1.z, g1.w};
    float ev[8] = {e0.x, e0.y, e0.z, e0.w, e1.x, e1.y, e1.z, e1.w};
    bf16x8 o;
#pragma unroll
    for (int j = 0; j < 8; ++j) {
      float xh = (ls[t0 + j][cl] - mean) * istd;
      o[j] = (__bf16)(xh * gv[j] + ev[j]);
    }
    *(bf16x8*)&xnb[(size_t)cg * 512 + bt + t0] = o;
  }
}

// ================= mega kernel: 4 phases, grid.sync between =================
__global__ __launch_bounds__(256, 3) void mega_k(
    const float* __restrict__ x, const float* __restrict__ g,
    const float* __restrict__ be, const float* __restrict__ cw,
    const float* __restrict__ w1, const float* __restrict__ w2,
    const float* __restrict__ w3, const float* __restrict__ w4,
    const float* __restrict__ b1, const float* __restrict__ b2,
    const float* __restrict__ b3, const float* __restrict__ b4,
    const float* __restrict__ cb, float* __restrict__ out,
    float* __restrict__ part, __bf16* __restrict__ xbf,
    __bf16* __restrict__ WtT, __bf16* __restrict__ XnT,
    __bf16* __restrict__ Y1T, __bf16* __restrict__ Z1T,
    __bf16* __restrict__ Z3T, __bf16* __restrict__ w1b,
    __bf16* __restrict__ w2b, __bf16* __restrict__ w3b,
    __bf16* __restrict__ w4b) {
  cg::grid_group gg = cg::this_grid();
  __shared__ __align__(16) char smem[33280];
  __bf16* As = (__bf16*)smem;
  __bf16* Bs = (__bf16*)(smem + 16384);
  const int G = gridDim.x;

  // P0: stats partials + xbf cast (256) + WtT prep (2048)
  for (int vb = blockIdx.x; vb < 2304; vb += G)
    pre1_body(vb, smem, x, part, xbf, cw, WtT);
  gg.sync();

  // P1: G3 (512) | norm (4096) | wprep (2560)
  for (int vb = blockIdx.x; vb < 7168; vb += G) {
    if (vb < 512)
      gemm_body<false, false, false, true, true>(vb, 1, As, Bs,
          xbf, 262144, WtT, 0, Z1T, 131072, cb, 1024, 256, 0);
    else if (vb < 4608)
      norm_body(vb - 512, smem, xbf, g, be, part, XnT);
    else
      wprep_body(vb - 4608, w1, w2, w3, w4, w1b, w2b, w3b, w4b);
  }
  gg.sync();

  // P2: G1 (1024) | G4 (512)
  for (int vb = blockIdx.x; vb < 1536; vb += G) {
    if (vb < 1024)
      gemm_body<true, true, true, false, true>(vb, 2, As, Bs,
          w1b, 0, XnT, 262144, Y1T, 262144, b1, 512, 512, 0);
    else
      gemm_body<true, true, true, false, true>(vb - 1024, 1, As, Bs,
          w3b, 0, Z1T, 131072, Z3T, 131072, b3, 256, 256, 0);
  }
  gg.sync();

  // P3: G2 (1024) | G5 (512)
  for (int vb = blockIdx.x; vb < 1536; vb += G) {
    if (vb < 1024)
      gemm_body<true, false, true, false, false>(vb, 2, As, Bs,
          w2b, 0, Y1T, 262144, out, 393216, b2, 512, 768, 0);
    else
      gemm_body<true, false, true, false, false>(vb - 1024, 1, As, Bs,
          w4b, 0, Z3T, 131072, out, 393216, b4, 256, 768, 512);
  }
}

extern "C" void kernel_launch(void* const* d_in, const int* in_sizes, int n_in,
                              void* d_out, int out_size, void* d_ws, size_t ws_size,
                              hipStream_t stream) {
  const float* x  = (const float*)d_in[0];
  const float* g  = (const float*)d_in[1];
  const float* be = (const float*)d_in[2];
  const float* w1 = (const float*)d_in[3];
  const float* b1 = (const float*)d_in[4];
  const float* w2 = (const float*)d_in[5];
  const float* b2 = (const float*)d_in[6];
  const float* cw = (const float*)d_in[7];
  const float* cb = (const float*)d_in[8];
  const float* w3 = (const float*)d_in[9];
  const float* b3 = (const float*)d_in[10];
  const float* w4 = (const float*)d_in[11];
  const float* b4 = (const float*)d_in[12];
  float* out = (float*)d_out;

  char* ws = (char*)d_ws;
  float*  part  = (float*)(ws + 4096);                 // 2 KB
  __bf16* w1b   = (__bf16*)(ws + (1 << 20));           // 512 KB
  __bf16* w2b   = (__bf16*)(ws + (1 << 20) + 524288);
  __bf16* w3b   = (__bf16*)(ws + (2 << 20));           // 128 KB
  __bf16* w4b   = (__bf16*)(ws + (2 << 20) + 131072);
  __bf16* WtT   = (__bf16*)(ws + (3 << 20));           // 1 MB   [512][1024]
  __bf16* xbf   = (__bf16*)(ws + ((size_t)4 << 20));   // 32 MB [B][256][1024]
  __bf16* XnT   = (__bf16*)(ws + ((size_t)36 << 20));  // 32 MB [B][512][512]
  __bf16* Y1T   = (__bf16*)(ws + ((size_t)68 << 20));  // 32 MB [B][512][512]
  __bf16* Z1T   = (__bf16*)(ws + ((size_t)100 << 20)); // 16 MB [B][512][256]
  __bf16* Z3T   = (__bf16*)(ws + ((size_t)116 << 20)); // 16 MB -> 132 MB total

  int nb = 0;
  hipOccupancyMaxActiveBlocksPerMultiprocessor(&nb, mega_k, 256, 0);
  if (nb < 1) nb = 1;
  long grid = (long)nb * 256;
  if (grid > 768) grid = 768;
  grid &= ~7L;                      // keep XCD-swizzle residue alignment
  if (grid < 8) grid = 8;

  void* args[] = {
      (void*)&x, (void*)&g, (void*)&be, (void*)&cw,
      (void*)&w1, (void*)&w2, (void*)&w3, (void*)&w4,
      (void*)&b1, (void*)&b2, (void*)&b3, (void*)&b4,
      (void*)&cb, (void*)&out,
      (void*)&part, (void*)&xbf, (void*)&WtT, (void*)&XnT,
      (void*)&Y1T, (void*)&Z1T, (void*)&Z3T,
      (void*)&w1b, (void*)&w2b, (void*)&w3b, (void*)&w4b};
  hipLaunchCooperativeKernel(mega_k, dim3((int)grid), dim3(256), args, 0, stream);
}

// Round 12
// 127.584 us; speedup vs baseline: 2.4811x; 2.4811x over previous
//
#include <hip/hip_runtime.h>
#include <hip/hip_bf16.h>

// MultiScaleTimeMixer: B=64, T=512, C=512, T2=256
// bf16 MFMA pipeline, intermediates TRANSPOSED ([N x K] for next GEMM).
// R12 = R9 (best: 128.9us) + nontemporal hints via ext_vector types:
//       out-stores (100MB, never re-read) and x-loads bypass L3.
// DAG: pre1 -> [G3|norm|wprep] -> [G1|G4] -> [G2|G5].

#define NB 64

typedef __bf16 bf16x8 __attribute__((ext_vector_type(8)));
typedef __bf16 bf16x4 __attribute__((ext_vector_type(4)));
typedef float f32x4 __attribute__((ext_vector_type(4)));

#define AS_GLOBAL __attribute__((address_space(1)))
#define AS_LDS    __attribute__((address_space(3)))

// ---- L1: per-batch partial stats + xbf cast (blocks 0..255) + WtT prep ----
__global__ void pre1_k(const float* __restrict__ x, float* __restrict__ part,
                       __bf16* __restrict__ xbf, const float* __restrict__ cw,
                       __bf16* __restrict__ WtT) {
  if (blockIdx.x < 256) {
    int bb = blockIdx.x;  // 4 per batch
    int b = bb >> 2, q = bb & 3;
    size_t base = (size_t)b * 262144 + (size_t)q * 65536;
    const f32x4* xb = (const f32x4*)(x + base);
    bf16x4* xo = (bf16x4*)(xbf + base);
    float s = 0.f, ss = 0.f;
    for (int it = 0; it < 64; ++it) {
      int idx = threadIdx.x + 256 * it;
      f32x4 v = __builtin_nontemporal_load(&xb[idx]);   // x never re-read
      s += (v[0] + v[1]) + (v[2] + v[3]);
      ss += (v[0] * v[0] + v[1] * v[1]) + (v[2] * v[2] + v[3] * v[3]);
      bf16x4 o;
      o[0] = (__bf16)v[0]; o[1] = (__bf16)v[1]; o[2] = (__bf16)v[2]; o[3] = (__bf16)v[3];
      xo[idx] = o;
    }
    __shared__ float ls[256], lss[256];
    ls[threadIdx.x] = s; lss[threadIdx.x] = ss;
    __syncthreads();
    for (int off = 128; off > 0; off >>= 1) {
      if (threadIdx.x < off) {
        ls[threadIdx.x] += ls[threadIdx.x + off];
        lss[threadIdx.x] += lss[threadIdx.x + off];
      }
      __syncthreads();
    }
    if (threadIdx.x == 0) { part[bb * 2] = ls[0]; part[bb * 2 + 1] = lss[0]; }
    return;
  }
  // WtT[o][k*512+i] = cw[o][i*2+k]   (B^T layout [512][1024])
  int idx = (blockIdx.x - 256) * 256 + threadIdx.x;  // 512*1024
  int o = idx >> 10, r = idx & 1023;
  int i = r & 511, k = r >> 9;
  WtT[idx] = (__bf16)cw[(size_t)o * 1024 + i * 2 + k];
}

// ---------------- GEMM body: A [MxK] rm, Bt [NxK] rm (bf16); D^T store ----------------
// 128x128 tile, 4 waves of 64x64 (4x4 frags). LDS: row r (128B), 16B-chunk s holds
// global chunk s ^ (r&7); gload_lds linear dest, source pre-swizzled (rule #21).
// XCD-chunked swizzle, runtime lgx (nwg%8==0). MASKK: tril A -> Kend = bm+128.
template <bool MASKK, bool HSW, bool ROWB, bool COLB, bool OUTBF>
__device__ __forceinline__ void gemm_body(
    int bid, int lgx, __bf16* As, __bf16* Bs,
    const __bf16* __restrict__ A, long sAb,
    const __bf16* __restrict__ Bt, long sBb,
    void* __restrict__ Cm, long sCb,
    const float* __restrict__ bias,
    int K, int ldc, int c_off) {
  const int tid = threadIdx.x;
  const int lane = tid & 63, wid = tid >> 6;
  const int wm = (wid >> 1) * 64, wn = (wid & 1) * 64;
  const int lr = lane & 15, lg = lane >> 4;

  const int nid = ((bid & 7) << (lgx + 5)) | (bid >> 3);
  const int bm = (nid & ((1 << lgx) - 1)) * 128;
  const int bn = ((nid >> lgx) & 3) * 128;
  const int bz = nid >> (lgx + 2);

  const int srg = lane >> 3;                  // row within 8-row group == (row&7)
  const int ssrc = ((lane & 7) ^ srg) << 3;   // pre-swizzled source chunk (elems)

  const __bf16* gA[4];
  const __bf16* gB[4];
#pragma unroll
  for (int p = 0; p < 4; ++p) {
    int row = p * 32 + wid * 8 + srg;
    gA[p] = A + (size_t)bz * sAb + (size_t)(bm + row) * K + ssrc;
    gB[p] = Bt + (size_t)bz * sBb + (size_t)(bn + row) * K + ssrc;
  }

  f32x4 acc[4][4] = {};

  const int Kend = MASKK ? (bm + 128) : K;   // tril: k >= bm+128 hits zeros in A
  for (int k0 = 0; k0 < Kend; k0 += 64) {
#pragma unroll
    for (int p = 0; p < 4; ++p) {
      __builtin_amdgcn_global_load_lds(
          (const AS_GLOBAL void*)gA[p],
          (AS_LDS void*)&As[(p * 32 + wid * 8) * 64], 16, 0, 0);
      __builtin_amdgcn_global_load_lds(
          (const AS_GLOBAL void*)gB[p],
          (AS_LDS void*)&Bs[(p * 32 + wid * 8) * 64], 16, 0, 0);
      gA[p] += 64;
      gB[p] += 64;
    }
    __syncthreads();
#pragma unroll
    for (int kk = 0; kk < 64; kk += 32) {
      bf16x8 af[4], bfv[4];
#pragma unroll
      for (int f = 0; f < 4; ++f) {
        int ar = wm + f * 16 + lr;
        af[f] = *(const bf16x8*)&As[ar * 64 + ((kk + lg * 8) ^ ((ar & 7) << 3))];
        int br = wn + f * 16 + lr;
        bfv[f] = *(const bf16x8*)&Bs[br * 64 + ((kk + lg * 8) ^ ((br & 7) << 3))];
      }
#pragma unroll
      for (int i = 0; i < 4; ++i)
#pragma unroll
        for (int j = 0; j < 4; ++j)
          acc[i][j] = __builtin_amdgcn_mfma_f32_16x16x32_bf16(af[i], bfv[j], acc[i][j], 0, 0, 0);
    }
    __syncthreads();
  }

  // epilogue: D[row][col]: col = lane&15 (+16j), row = (lane>>4)*4+r (+16i). store D^T.
#pragma unroll
  for (int i = 0; i < 4; ++i) {
    int row0 = bm + wm + i * 16 + lg * 4;
    float rb0 = 0.f, rb1 = 0.f, rb2 = 0.f, rb3 = 0.f;
    if (ROWB) { rb0 = bias[row0]; rb1 = bias[row0 + 1]; rb2 = bias[row0 + 2]; rb3 = bias[row0 + 3]; }
#pragma unroll
    for (int j = 0; j < 4; ++j) {
      int col = bn + wn + j * 16 + lr;
      float cbv = COLB ? bias[col] : 0.f;
      float v[4] = {acc[i][j][0] + rb0 + cbv, acc[i][j][1] + rb1 + cbv,
                    acc[i][j][2] + rb2 + cbv, acc[i][j][3] + rb3 + cbv};
      if (HSW) {
#pragma unroll
        for (int r = 0; r < 4; ++r) {
          float u = fminf(fmaxf(v[r] + 3.f, 0.f), 6.f);
          v[r] = v[r] * u * (1.f / 6.f);
        }
      }
      if (OUTBF) {
        __bf16* C = (__bf16*)Cm + (size_t)bz * sCb;
        bf16x4 o;
        o[0] = (__bf16)v[0]; o[1] = (__bf16)v[1]; o[2] = (__bf16)v[2]; o[3] = (__bf16)v[3];
        *(bf16x4*)&C[(size_t)col * ldc + c_off + row0] = o;
      } else {
        float* C = (float*)Cm + (size_t)bz * sCb;
        // final output: never re-read -> nontemporal, keep L3 for intermediates
        f32x4 o = {v[0], v[1], v[2], v[3]};
        __builtin_nontemporal_store(o, (f32x4*)&C[(size_t)col * ldc + c_off + row0]);
      }
    }
  }
}

// ---- norm body: XnT[b][c][t] = bf16(((bf16(x)-mean)*istd)*g + be), 64x64 tile ----
__device__ __forceinline__ void norm_body(
    int bid, char* smem,
    const __bf16* __restrict__ xbf, const float* __restrict__ g,
    const float* __restrict__ be, const float* __restrict__ part,
    __bf16* __restrict__ XnT) {
  float (*ls)[65] = (float(*)[65])smem;
  int b = bid >> 6;
  int r = bid & 63;
  int bc = (r & 7) * 64;   // c tile
  int bt = (r >> 3) * 64;  // t tile
  int tid = threadIdx.x;
  float s = 0.f, ss = 0.f;
#pragma unroll
  for (int q = 0; q < 4; ++q) { s += part[(b * 4 + q) * 2]; ss += part[(b * 4 + q) * 2 + 1]; }
  float mean = s * (1.f / 262144.f);
  float istd = rsqrtf(ss * (1.f / 262144.f) - mean * mean + 1e-5f);

  const __bf16* xb = xbf + (size_t)b * 262144;
  int row = tid >> 3;          // 0..31
  int ch = (tid & 7) * 8;      // c chunk
#pragma unroll
  for (int p = 0; p < 2; ++p) {
    int t = p * 32 + row;
    bf16x8 v = *(const bf16x8*)&xb[(size_t)(bt + t) * 512 + bc + ch];
#pragma unroll
    for (int j = 0; j < 8; ++j) ls[t][ch + j] = (float)v[j];
  }
  __syncthreads();
  int cr = tid >> 3;
  int t0 = (tid & 7) * 8;
  __bf16* xnb = XnT + (size_t)b * 262144;
#pragma unroll
  for (int p = 0; p < 2; ++p) {
    int cg = bc + p * 32 + cr;
    int cl = p * 32 + cr;
    float4 g0 = *(const float4*)&g[(size_t)cg * 512 + bt + t0];
    float4 g1 = *(const float4*)&g[(size_t)cg * 512 + bt + t0 + 4];
    float4 e0 = *(const float4*)&be[(size_t)cg * 512 + bt + t0];
    float4 e1 = *(const float4*)&be[(size_t)cg * 512 + bt + t0 + 4];
    float gv[8] = {g0.x, g0.y, g0.z, g0.w, g1.x, g1.y, g1.z, g1.w};
    float ev[8] = {e0.x, e0.y, e0.z, e0.w, e1.x, e1.y, e1.z, e1.w};
    bf16x8 o;
#pragma unroll
    for (int j = 0; j < 8; ++j) {
      float xh = (ls[t0 + j][cl] - mean) * istd;
      o[j] = (__bf16)(xh * gv[j] + ev[j]);
    }
    *(bf16x8*)&xnb[(size_t)cg * 512 + bt + t0] = o;
  }
}

// ---- L2: G3 (blocks 0..511) | norm (512..4607) | w-prep (4608..7167) ----
__global__ __launch_bounds__(256, 3) void fused_g3_norm_k(
    const __bf16* __restrict__ xbf, const __bf16* __restrict__ WtT,
    __bf16* __restrict__ Z1T, const float* __restrict__ cb,
    const float* __restrict__ g, const float* __restrict__ be,
    const float* __restrict__ part, __bf16* __restrict__ XnT,
    const float* __restrict__ w1, const float* __restrict__ w2,
    const float* __restrict__ w3, const float* __restrict__ w4,
    __bf16* __restrict__ w1b, __bf16* __restrict__ w2b,
    __bf16* __restrict__ w3b, __bf16* __restrict__ w4b) {
  __shared__ __align__(16) char smem[33280];
  __bf16* As = (__bf16*)smem;
  __bf16* Bs = (__bf16*)(smem + 16384);
  int bid = blockIdx.x;
  if (bid < 512) {
    gemm_body<false, false, false, true, true>(bid, 1, As, Bs,
        xbf, 262144, WtT, 0, Z1T, 131072, cb, 1024, 256, 0);
  } else if (bid < 4608) {
    norm_body(bid - 512, smem, xbf, g, be, part, XnT);
  } else {
    int idx = (bid - 4608) * 256 + threadIdx.x;
    if (idx < 262144) { int i = idx >> 9, j = idx & 511; w1b[idx] = (__bf16)(j <= i ? w1[idx] : 0.f); return; }
    idx -= 262144;
    if (idx < 262144) { int i = idx >> 9, j = idx & 511; w2b[idx] = (__bf16)(j <= i ? w2[idx] : 0.f); return; }
    idx -= 262144;
    if (idx < 65536) { int i = idx >> 8, j = idx & 255; w3b[idx] = (__bf16)(j <= i ? w3[idx] : 0.f); return; }
    idx -= 65536;
    { int i = idx >> 8, j = idx & 255; w4b[idx] = (__bf16)(j <= i ? w4[idx] : 0.f); }
  }
}

// ---- L3: G1 (blocks 0..1023) | G4 (blocks 1024..1535) ----
__global__ __launch_bounds__(256, 3) void fused_g1_g4_k(
    const __bf16* __restrict__ w1b, const __bf16* __restrict__ XnT,
    __bf16* __restrict__ Y1T, const float* __restrict__ b1,
    const __bf16* __restrict__ w3b, const __bf16* __restrict__ Z1T,
    __bf16* __restrict__ Z3T, const float* __restrict__ b3) {
  __shared__ __align__(16) char smem[32768];
  __bf16* As = (__bf16*)smem;
  __bf16* Bs = (__bf16*)(smem + 16384);
  int bid = blockIdx.x;
  if (bid < 1024)
    gemm_body<true, true, true, false, true>(bid, 2, As, Bs,
        w1b, 0, XnT, 262144, Y1T, 262144, b1, 512, 512, 0);
  else
    gemm_body<true, true, true, false, true>(bid - 1024, 1, As, Bs,
        w3b, 0, Z1T, 131072, Z3T, 131072, b3, 256, 256, 0);
}

// ---- L4: G2 (blocks 0..1023) | G5 (blocks 1024..1535) ----
__global__ __launch_bounds__(256, 3) void fused_g2_g5_k(
    const __bf16* __restrict__ w2b, const __bf16* __restrict__ Y1T,
    float* __restrict__ out, const float* __restrict__ b2,
    const __bf16* __restrict__ w4b, const __bf16* __restrict__ Z3T,
    const float* __restrict__ b4) {
  __shared__ __align__(16) char smem[32768];
  __bf16* As = (__bf16*)smem;
  __bf16* Bs = (__bf16*)(smem + 16384);
  int bid = blockIdx.x;
  if (bid < 1024)
    gemm_body<true, false, true, false, false>(bid, 2, As, Bs,
        w2b, 0, Y1T, 262144, out, 393216, b2, 512, 768, 0);
  else
    gemm_body<true, false, true, false, false>(bid - 1024, 1, As, Bs,
        w4b, 0, Z3T, 131072, out, 393216, b4, 256, 768, 512);
}

extern "C" void kernel_launch(void* const* d_in, const int* in_sizes, int n_in,
                              void* d_out, int out_size, void* d_ws, size_t ws_size,
                              hipStream_t stream) {
  const float* x  = (const float*)d_in[0];
  const float* g  = (const float*)d_in[1];
  const float* be = (const float*)d_in[2];
  const float* w1 = (const float*)d_in[3];
  const float* b1 = (const float*)d_in[4];
  const float* w2 = (const float*)d_in[5];
  const float* b2 = (const float*)d_in[6];
  const float* cw = (const float*)d_in[7];
  const float* cb = (const float*)d_in[8];
  const float* w3 = (const float*)d_in[9];
  const float* b3 = (const float*)d_in[10];
  const float* w4 = (const float*)d_in[11];
  const float* b4 = (const float*)d_in[12];
  float* out = (float*)d_out;

  char* ws = (char*)d_ws;
  float*  part  = (float*)(ws + 4096);                 // 2 KB
  __bf16* w1b   = (__bf16*)(ws + (1 << 20));           // 512 KB
  __bf16* w2b   = (__bf16*)(ws + (1 << 20) + 524288);
  __bf16* w3b   = (__bf16*)(ws + (2 << 20));           // 128 KB
  __bf16* w4b   = (__bf16*)(ws + (2 << 20) + 131072);
  __bf16* WtT   = (__bf16*)(ws + (3 << 20));           // 1 MB   [512][1024]
  __bf16* xbf   = (__bf16*)(ws + ((size_t)4 << 20));   // 32 MB [B][256][1024]
  __bf16* XnT   = (__bf16*)(ws + ((size_t)36 << 20));  // 32 MB [B][512][512]
  __bf16* Y1T   = (__bf16*)(ws + ((size_t)68 << 20));  // 32 MB [B][512][512]
  __bf16* Z1T   = (__bf16*)(ws + ((size_t)100 << 20)); // 16 MB [B][512][256]
  __bf16* Z3T   = (__bf16*)(ws + ((size_t)116 << 20)); // 16 MB -> 132 MB total

  // L1: stats partials + xbf cast + WtT prep   (256 + 2048 blocks)
  pre1_k<<<2304, 256, 0, stream>>>(x, part, xbf, cw, WtT);
  // L2: G3 (xbf @ WtT -> Z1T) || norm (xbf -> XnT) || w1..w4 prep
  fused_g3_norm_k<<<7168, 256, 0, stream>>>(xbf, WtT, Z1T, cb, g, be, part, XnT,
                                            w1, w2, w3, w4, w1b, w2b, w3b, w4b);
  // L3: G1 (w1 @ Xn -> Y1T) || G4 (w3 @ Z1 -> Z3T)
  fused_g1_g4_k<<<1536, 256, 0, stream>>>(w1b, XnT, Y1T, b1, w3b, Z1T, Z3T, b3);
  // L4: G2 (w2 @ Y1 -> out[:,:,0:512]) || G5 (w4 @ Z3 -> out[:,:,512:768])
  fused_g2_g5_k<<<1536, 256, 0, stream>>>(w2b, Y1T, out, b2, w4b, Z3T, b4);
}